// Round 1
// baseline (1273.573 us; speedup 1.0000x reference)
//
#include <hip/hip_runtime.h>
#include <hip/hip_fp16.h>

#define BATCH   8192
#define FDIM    512
#define NTREE   64
#define NODES   63
#define ODIM    128
#define ROWS    8      // batch rows per block

__device__ __forceinline__ float smooth_step_f(float t) {
    float tc = fminf(fmaxf(t, -0.5f), 0.5f);
    // -2*tc^3 + 1.5*tc + 0.5 = tc*(1.5 - 2*tc*tc) + 0.5
    return fmaf(tc, fmaf(-2.0f * tc, tc, 1.5f), 0.5f);
}

__device__ __forceinline__ void build_prob(const __half (&srow)[NODES][NTREE],
                                           int lane, float (&pr)[64]) {
    pr[0] = 1.0f;
    int base = 0;
    #pragma unroll
    for (int lvl = 0; lvl < 6; ++lvl) {
        const int width = 1 << lvl;
        #pragma unroll
        for (int i = width - 1; i >= 0; --i) {
            float s = __half2float(srow[base + i][lane]);
            float p = pr[i];
            pr[2 * i]     = p * s;
            pr[2 * i + 1] = p * (1.0f - s);
        }
        base += width;
    }
}

__global__ __launch_bounds__(256, 2)
void soft_tree_kernel(const float* __restrict__ x,
                      const float* __restrict__ Wn,
                      const float* __restrict__ bn,
                      const float* __restrict__ Wl,
                      float* __restrict__ out)
{
    __shared__ __half s_lds[ROWS][NODES][NTREE];   // 64512 B

    const int lane = threadIdx.x & 63;   // = tree index t
    const int w    = threadIdx.x >> 6;   // wave id 0..3
    const long row0 = (long)blockIdx.x * ROWS;

    // ---------- phase 1: z -> s for all 63 nodes, 8 rows, lane = tree ----------
    // waves split nodes; per node: 512-long dot for 8 rows sharing each W load
    for (int n = w; n < NODES; n += 4) {
        const float* wp = Wn + ((long)n * FDIM) * NTREE + lane;  // W[n][f][lane]
        const float* xp = x + row0 * FDIM;
        float acc[ROWS];
        #pragma unroll
        for (int r = 0; r < ROWS; ++r) acc[r] = 0.0f;
        #pragma unroll 8
        for (int f = 0; f < FDIM; ++f) {
            float wv = wp[(long)f * NTREE];          // coalesced across lanes
            #pragma unroll
            for (int r = 0; r < ROWS; ++r)
                acc[r] = fmaf(xp[r * FDIM + f], wv, acc[r]);  // x uniform -> s_load
        }
        float bias = bn[n * NTREE + lane];
        #pragma unroll
        for (int r = 0; r < ROWS; ++r)
            s_lds[r][n][lane] = __float2half(smooth_step_f(acc[r] + bias));
    }
    __syncthreads();

    // ---------- phase 2: prob (in regs) + leaf contraction, 2 rows per wave ----------
    const int r0 = w * 2;
    const int r1 = w * 2 + 1;
    float pr0[64], pr1[64];
    build_prob(s_lds[r0], lane, pr0);
    build_prob(s_lds[r1], lane, pr1);

    for (int o = 0; o < ODIM; ++o) {
        const float* wlp = Wl + (long)o * NTREE + lane;   // W_leaf[l][o][lane]
        float c0 = 0.0f, c1 = 0.0f;
        #pragma unroll
        for (int l = 0; l < 64; ++l) {
            float wv = wlp[(long)l * (ODIM * NTREE)];     // coalesced across lanes
            c0 = fmaf(pr0[l], wv, c0);
            c1 = fmaf(pr1[l], wv, c1);
        }
        // 64-lane butterfly reduction over trees
        #pragma unroll
        for (int off = 32; off > 0; off >>= 1) {
            c0 += __shfl_xor(c0, off, 64);
            c1 += __shfl_xor(c1, off, 64);
        }
        if (lane == 0) {
            out[(row0 + r0) * ODIM + o] = c0;
            out[(row0 + r1) * ODIM + o] = c1;
        }
    }
}

extern "C" void kernel_launch(void* const* d_in, const int* in_sizes, int n_in,
                              void* d_out, int out_size, void* d_ws, size_t ws_size,
                              hipStream_t stream) {
    const float* x  = (const float*)d_in[0];
    const float* Wn = (const float*)d_in[1];
    const float* bn = (const float*)d_in[2];
    const float* Wl = (const float*)d_in[3];
    float* out = (float*)d_out;

    dim3 grid(BATCH / ROWS);   // 1024
    dim3 block(256);
    soft_tree_kernel<<<grid, block, 0, stream>>>(x, Wn, bn, Wl, out);
}